// Round 1
// baseline (255.573 us; speedup 1.0000x reference)
//
#include <hip/hip_runtime.h>
#include <math.h>

#define HW_ 16384
#define EPS_WH 1e-7f
#define MAX_WH 1e7f

__global__ __launch_bounds__(256) void gwd_stage1(
    const float* __restrict__ pred_hm,     // B * 1 * 128 * 128
    const float* __restrict__ pred_ab,     // B * 2 * 16384
    const float* __restrict__ pred_trig,   // B * 2 * 16384
    const float* __restrict__ pred_center, // B * 2
    const float* __restrict__ target,      // B * 5
    float* __restrict__ loss_out)          // B
{
    const int b   = blockIdx.x;
    const int tid = threadIdx.x;

    // ---- per-batch argmax over 16384 contiguous floats (float4 loads) ----
    const float4* hm = (const float4*)(pred_hm + (size_t)b * HW_);
    float best = -INFINITY;
    int   bidx = 0x7fffffff;
    #pragma unroll
    for (int i = 0; i < 16; ++i) {
        const int v4i  = tid + i * 256;       // increasing index per thread
        const float4 v = hm[v4i];
        const int base = v4i * 4;
        if (v.x > best) { best = v.x; bidx = base;     }
        if (v.y > best) { best = v.y; bidx = base + 1; }
        if (v.z > best) { best = v.z; bidx = base + 2; }
        if (v.w > best) { best = v.w; bidx = base + 3; }
    }

    // wave (64-lane) argmax reduce, first-occurrence tie-break
    #pragma unroll
    for (int off = 32; off > 0; off >>= 1) {
        const float ov = __shfl_down(best, off, 64);
        const int   oi = __shfl_down(bidx, off, 64);
        if (ov > best || (ov == best && oi < bidx)) { best = ov; bidx = oi; }
    }

    __shared__ float s_val[4];
    __shared__ int   s_idx[4];
    if ((tid & 63) == 0) { s_val[tid >> 6] = best; s_idx[tid >> 6] = bidx; }
    __syncthreads();

    if (tid == 0) {
        best = s_val[0]; bidx = s_idx[0];
        #pragma unroll
        for (int w = 1; w < 4; ++w) {
            const float ov = s_val[w]; const int oi = s_idx[w];
            if (ov > best || (ov == best && oi < bidx)) { best = ov; bidx = oi; }
        }
        const int ind = bidx;

        // ---- gather ab / trig at argmax ----
        const float* ab = pred_ab   + (size_t)b * 2 * HW_;
        const float* tg = pred_trig + (size_t)b * 2 * HW_;
        const float ab0   = ab[ind];
        const float ab1   = ab[HW_ + ind];
        const float sin2A = tg[ind];
        const float cos2A = tg[HW_ + ind];

        // pred angle: rad2deg(atan2/2) then deg2rad cancels
        const float r_p = 0.5f * atan2f(sin2A, cos2A);

        // pred wh = 2*ab, clipped; sdiag = 0.5*wh
        const float wp0 = fminf(fmaxf(2.0f * ab0, EPS_WH), MAX_WH);
        const float wp1 = fminf(fmaxf(2.0f * ab1, EPS_WH), MAX_WH);
        const float sp0 = 0.5f * wp0, sp1 = 0.5f * wp1;

        const float cx = pred_center[(size_t)b * 2 + 0];
        const float cy = pred_center[(size_t)b * 2 + 1];

        const float* t = target + (size_t)b * 5;
        const float tx = t[0], ty = t[1];
        const float wt0 = fminf(fmaxf(t[2], EPS_WH), MAX_WH);
        const float wt1 = fminf(fmaxf(t[3], EPS_WH), MAX_WH);
        const float st0 = 0.5f * wt0, st1 = 0.5f * wt1;
        const float r_t = t[4] * 0.017453292519943295f; // deg2rad

        const float cp = cosf(r_p), sn = sinf(r_p);
        const float ct = cosf(r_t), snt = sinf(r_t);

        const float apm = sp0 * sp0, bpm = sp1 * sp1;   // sp^2
        const float atm = st0 * st0, btm = st1 * st1;   // st^2

        // Sigma = R diag(s^2) R^T for R=[[c,-s],[s,c]]
        const float Sp00 = cp * cp * apm + sn * sn * bpm;
        const float Sp11 = sn * sn * apm + cp * cp * bpm;
        const float Sp01 = cp * sn * (apm - bpm);
        const float St00 = ct * ct * atm + snt * snt * btm;
        const float St11 = snt * snt * atm + ct * ct * btm;
        const float St01 = ct * snt * (atm - btm);

        const float tr = Sp00 * St00 + Sp11 * St11 + 2.0f * Sp01 * St01;
        const float det_sqrt = sqrtf(fmaxf(sp0 * sp1 * st0 * st1, 0.0f));
        const float whr = (apm + bpm) + (atm + btm)
                        - 2.0f * sqrtf(fmaxf(tr + 2.0f * det_sqrt, 0.0f));
        const float dx = cx - tx, dy = cy - ty;
        const float dist = fmaxf(dx * dx + dy * dy + whr, 0.0f);
        loss_out[b] = 1.0f - 1.0f / (1.0f + dist);
    }
}

__global__ __launch_bounds__(256) void gwd_stage2(
    const float* __restrict__ losses, float* __restrict__ out)
{
    const int tid = threadIdx.x;
    float s = losses[tid] + losses[tid + 256] + losses[tid + 512] + losses[tid + 768];
    #pragma unroll
    for (int off = 32; off > 0; off >>= 1) s += __shfl_down(s, off, 64);
    __shared__ float ws[4];
    if ((tid & 63) == 0) ws[tid >> 6] = s;
    __syncthreads();
    if (tid == 0) out[0] = (ws[0] + ws[1] + ws[2] + ws[3]) * (1.0f / 1024.0f);
}

extern "C" void kernel_launch(void* const* d_in, const int* in_sizes, int n_in,
                              void* d_out, int out_size, void* d_ws, size_t ws_size,
                              hipStream_t stream) {
    const float* pred_hm     = (const float*)d_in[0];
    const float* pred_ab     = (const float*)d_in[1];
    const float* pred_trig   = (const float*)d_in[2];
    const float* pred_center = (const float*)d_in[3];
    const float* target      = (const float*)d_in[4];
    float* losses = (float*)d_ws;          // 1024 floats
    float* out    = (float*)d_out;

    const int B = 1024;
    gwd_stage1<<<B, 256, 0, stream>>>(pred_hm, pred_ab, pred_trig,
                                      pred_center, target, losses);
    gwd_stage2<<<1, 256, 0, stream>>>(losses, out);
}